// Round 1
// 457.492 us; speedup vs baseline: 1.0379x; 1.0379x over previous
//
#include <hip/hip_runtime.h>

typedef __bf16 bf16x8 __attribute__((ext_vector_type(8)));
typedef __bf16 bf16x4 __attribute__((ext_vector_type(4)));
typedef float f32x4 __attribute__((ext_vector_type(4)));

#define BH_TOT 64
#define SEQ 8192
#define DIM 64
#define NCH 16                 // n-chunks per bh in phase 1
#define CHN (SEQ / NCH)        // 512 rows per chunk
#define ROWS 64                // rows per staging round
#define NR (CHN / ROWS)        // 8 rounds per block
#define KV_STRIDE 68           // fp32 row stride of KV workspace (cols 0..64 used)
#define KV_ROWS 128

// ---------------------------------------------------------------------------
// Phase 1 (v2): partial KV[128][64] + Ksum[128] per (b,h) via fp32 atomics.
// Restructured for latency hiding:
//   - 512 threads (8 waves), 1 feature-tile per wave -> acc = 20 VGPR
//   - __launch_bounds__(512,8) forces VGPR<=64 -> 4 blocks/CU = 32 waves = 100%
//   - 64-row tiles (8 rounds, 2 barriers each instead of 16x2)
//   - register prefetch: tile t+1's global loads issue right after tile t's
//     conversion, so HBM latency hides under write+barriers+frags+MFMA
// ---------------------------------------------------------------------------
__global__ __launch_bounds__(512, 8) void fla_ph1(const float* __restrict__ K,
                                                  const float* __restrict__ V,
                                                  float* __restrict__ kvf) {
  const int blk = blockIdx.x;
  const int bh = blk / NCH;
  const int ch = blk % NCH;
  const float* Kp = K + (size_t)bh * SEQ * DIM + (size_t)ch * CHN * DIM;
  const float* Vp = V + (size_t)bh * SEQ * DIM + (size_t)ch * CHN * DIM;

  __shared__ __bf16 Kb[ROWS][68];   // 68-pad: frag reads land 2-way (free)
  __shared__ __bf16 Vb[ROWS][68];

  const int tid = threadIdx.x;
  const int lane = tid & 63;
  const int w = tid >> 6;           // 0..7: feature tile (features w*16..w*16+15)
  const int quad = lane >> 4;
  const int col = lane & 15;

  // staging geometry: 1024 float4 per array, 2 per thread
  const int r0 = tid >> 4;          // 0..31
  const int c0 = (tid & 15) << 2;   // 0,4,..,60
  const int off0 = r0 * DIM + c0;
  const int off1 = off0 + 32 * DIM; // rows 32..63

  f32x4 acc[5];
#pragma unroll
  for (int nt = 0; nt < 5; ++nt) acc[nt] = (f32x4){0.f, 0.f, 0.f, 0.f};

  // constant B fragment for the ones-column (global col 64 of [V | 1])
  bf16x8 bones;
#pragma unroll
  for (int j = 0; j < 8; ++j) bones[j] = (__bf16)0.f;
  if (col == 0) {
#pragma unroll
    for (int j = 0; j < 8; ++j) bones[j] = (__bf16)1.0f;
  }

  const int kcol = ((w & 3) << 4) + col;  // K column feeding this wave's feature
  const bool neg = (w >= 4);              // waves 4..7: features 64..127 = relu(-K)

  // prologue: tile 0 loads in flight
  float4 pk0 = *(const float4*)(Kp + off0);
  float4 pk1 = *(const float4*)(Kp + off1);
  float4 pv0 = *(const float4*)(Vp + off0);
  float4 pv1 = *(const float4*)(Vp + off1);

  for (int s = 0; s < NR; ++s) {
    // convert current tile (implicit vmcnt wait on the 4 loads)
    bf16x4 kb0, kb1, vb0, vb1;
    kb0[0] = (__bf16)pk0.x; kb0[1] = (__bf16)pk0.y; kb0[2] = (__bf16)pk0.z; kb0[3] = (__bf16)pk0.w;
    kb1[0] = (__bf16)pk1.x; kb1[1] = (__bf16)pk1.y; kb1[2] = (__bf16)pk1.z; kb1[3] = (__bf16)pk1.w;
    vb0[0] = (__bf16)pv0.x; vb0[1] = (__bf16)pv0.y; vb0[2] = (__bf16)pv0.z; vb0[3] = (__bf16)pv0.w;
    vb1[0] = (__bf16)pv1.x; vb1[1] = (__bf16)pv1.y; vb1[2] = (__bf16)pv1.z; vb1[3] = (__bf16)pv1.w;

    // prefetch tile s+1 into the now-free registers (fire-and-forget until
    // next round's conversion) — latency hides under everything below
    if (s + 1 < NR) {
      const float* Kn = Kp + (s + 1) * ROWS * DIM;
      const float* Vn = Vp + (s + 1) * ROWS * DIM;
      pk0 = *(const float4*)(Kn + off0);
      pk1 = *(const float4*)(Kn + off1);
      pv0 = *(const float4*)(Vn + off0);
      pv1 = *(const float4*)(Vn + off1);
    }

    __syncthreads();  // previous round's LDS readers done
    *(bf16x4*)&Kb[r0][c0]      = kb0;
    *(bf16x4*)&Kb[r0 + 32][c0] = kb1;
    *(bf16x4*)&Vb[r0][c0]      = vb0;
    *(bf16x4*)&Vb[r0 + 32][c0] = vb1;
    __syncthreads();

    // compute: two 32-row K-slabs
#pragma unroll
    for (int sl = 0; sl < 2; ++sl) {
      bf16x8 a;
#pragma unroll
      for (int j = 0; j < 8; ++j) {
        int rr = sl * 32 + quad * 8 + j;
        float kv = (float)Kb[rr][kcol];
        if (neg) kv = -kv;
        a[j] = (__bf16)fmaxf(kv, 0.f);
      }
#pragma unroll
      for (int nt = 0; nt < 4; ++nt) {
        bf16x8 b;
#pragma unroll
        for (int j = 0; j < 8; ++j)
          b[j] = Vb[sl * 32 + quad * 8 + j][col + nt * 16];
        acc[nt] = __builtin_amdgcn_mfma_f32_16x16x32_bf16(a, b, acc[nt], 0, 0, 0);
      }
      acc[4] = __builtin_amdgcn_mfma_f32_16x16x32_bf16(a, bones, acc[4], 0, 0, 0);
    }
  }

  // C/D layout: col = lane&15 (N), row = quad*4 + reg (M)  [measured m89/m91]
  float* dst = kvf + (size_t)bh * KV_ROWS * KV_STRIDE;
  const int feat = w * 16 + quad * 4;
#pragma unroll
  for (int nt = 0; nt < 5; ++nt) {
    int c = nt * 16 + col;
    if (c <= 64) {
#pragma unroll
      for (int r = 0; r < 4; ++r)
        atomicAdd(&dst[(size_t)(feat + r) * KV_STRIDE + c], acc[nt][r]);
    }
  }
}

// ---------------------------------------------------------------------------
// Phase 2 (unchanged): out[n][m] = (Qf[n] @ KV[:,m]) / (Qf[n] @ Ksum + 1e-6)
// ---------------------------------------------------------------------------
__global__ __launch_bounds__(256) void fla_ph2(const float* __restrict__ Q,
                                               const float* __restrict__ kvf,
                                               float* __restrict__ out) {
  const int blk = blockIdx.x;
  const int bh = blk >> 5;
  const int rb = blk & 31;                  // 32 row-blocks of 256 rows
  const float* Qp = Q + (size_t)bh * SEQ * DIM + (size_t)rb * 256 * DIM;
  float* Op = out + (size_t)bh * SEQ * DIM + (size_t)rb * 256 * DIM;

  __shared__ __bf16 kvb[128][66];           // cols 0..63 = KV, 64 = Ksum, 65 = pad
  const float* src = kvf + (size_t)bh * KV_ROWS * KV_STRIDE;
  for (int i = threadIdx.x; i < 128 * 66; i += 256) {
    int k = i / 66;
    int c = i - k * 66;
    float v = (c <= 64) ? src[(size_t)k * KV_STRIDE + c] : 0.f;
    kvb[k][c] = (__bf16)v;
  }
  __syncthreads();

  const int lane = threadIdx.x & 63;
  const int w = threadIdx.x >> 6;
  const int quad = lane >> 4;
  const int col = lane & 15;

  // B[k][n]: k = kt*32 + quad*8 + j, n = col (+16*nt)
  bf16x8 bfr[4][5];
#pragma unroll
  for (int kt = 0; kt < 4; ++kt) {
#pragma unroll
    for (int j = 0; j < 8; ++j) {
      int k = kt * 32 + quad * 8 + j;
      bfr[kt][0][j] = kvb[k][col];
      bfr[kt][1][j] = kvb[k][col + 16];
      bfr[kt][2][j] = kvb[k][col + 32];
      bfr[kt][3][j] = kvb[k][col + 48];
      bfr[kt][4][j] = (col == 0) ? kvb[k][64] : (__bf16)0.f;
    }
  }

#pragma unroll
  for (int mt = 0; mt < 4; ++mt) {
    // A-frag loads: lane reads Q[row = base + col][quad*8 .. +7] — the wave's
    // two dwordx4 per frag tile perfectly cover 16 rows x 128B contiguous.
    const float* qrow = Qp + (size_t)(w * 64 + mt * 16 + col) * DIM;
    float4 q0 = *(const float4*)(qrow + quad * 8);
    float4 q1 = *(const float4*)(qrow + quad * 8 + 4);
    float4 q2 = *(const float4*)(qrow + 32 + quad * 8);
    float4 q3 = *(const float4*)(qrow + 32 + quad * 8 + 4);
    float qv[16];
    *(float4*)&qv[0] = q0;  *(float4*)&qv[4] = q1;
    *(float4*)&qv[8] = q2;  *(float4*)&qv[12] = q3;
    bf16x8 a0, a1, a2, a3;   // kt0: relu(q0..31) kt1: relu(q32..63) kt2/3: relu(-q)
#pragma unroll
    for (int j = 0; j < 8; ++j) {
      a0[j] = (__bf16)fmaxf(qv[j], 0.f);
      a2[j] = (__bf16)fmaxf(-qv[j], 0.f);
      a1[j] = (__bf16)fmaxf(qv[8 + j], 0.f);
      a3[j] = (__bf16)fmaxf(-qv[8 + j], 0.f);
    }
    f32x4 acc[5];
#pragma unroll
    for (int nt = 0; nt < 5; ++nt) acc[nt] = (f32x4){0.f, 0.f, 0.f, 0.f};
#pragma unroll
    for (int nt = 0; nt < 5; ++nt) {
      acc[nt] = __builtin_amdgcn_mfma_f32_16x16x32_bf16(a0, bfr[0][nt], acc[nt], 0, 0, 0);
      acc[nt] = __builtin_amdgcn_mfma_f32_16x16x32_bf16(a1, bfr[1][nt], acc[nt], 0, 0, 0);
      acc[nt] = __builtin_amdgcn_mfma_f32_16x16x32_bf16(a2, bfr[2][nt], acc[nt], 0, 0, 0);
      acc[nt] = __builtin_amdgcn_mfma_f32_16x16x32_bf16(a3, bfr[3][nt], acc[nt], 0, 0, 0);
    }
    // normalizer lives in N-tile 4, col 0 → lane (quad<<4), same reg index
    float inv[4];
#pragma unroll
    for (int r = 0; r < 4; ++r) {
      float nrm = __shfl((float)acc[4][r], lane & 48, 64);
      inv[r] = 1.0f / (nrm + 1e-6f);
    }
    float* orow = Op + (size_t)(w * 64 + mt * 16) * DIM;
#pragma unroll
    for (int nt = 0; nt < 4; ++nt)
#pragma unroll
      for (int r = 0; r < 4; ++r)
        orow[(size_t)(quad * 4 + r) * DIM + nt * 16 + col] = acc[nt][r] * inv[r];
  }
}

extern "C" void kernel_launch(void* const* d_in, const int* in_sizes, int n_in,
                              void* d_out, int out_size, void* d_ws, size_t ws_size,
                              hipStream_t stream) {
  const float* Q = (const float*)d_in[0];
  const float* K = (const float*)d_in[1];
  const float* V = (const float*)d_in[2];
  float* out = (float*)d_out;
  float* kvf = (float*)d_ws;  // 64 * 128 * 68 fp32 = 2.23 MB

  hipMemsetAsync(kvf, 0, (size_t)BH_TOT * KV_ROWS * KV_STRIDE * sizeof(float), stream);
  fla_ph1<<<dim3(BH_TOT * NCH), dim3(512), 0, stream>>>(K, V, kvf);
  fla_ph2<<<dim3(BH_TOT * 32), dim3(256), 0, stream>>>(Q, kvf, out);
}

// Round 2
// 420.289 us; speedup vs baseline: 1.1298x; 1.0885x over previous
//
#include <hip/hip_runtime.h>

typedef __bf16 bf16x8 __attribute__((ext_vector_type(8)));
typedef __bf16 bf16x4 __attribute__((ext_vector_type(4)));
typedef float f32x4 __attribute__((ext_vector_type(4)));

#define BH_TOT 64
#define SEQ 8192
#define DIM 64
#define NCH 16                 // n-chunks per bh in phase 1
#define CHN (SEQ / NCH)        // 512 rows per chunk
#define ROWS 64                // rows per staging round
#define NR (CHN / ROWS)        // 8 rounds per block
#define PART_STRIDE 68         // fp32 row stride of per-chunk partials (cols 0..64 used)
#define KV_ROWS 128
#define RED_COLS 66            // bf16 reduced layout: 0..63 KV, 64 Ksum, 65 pad(0)

// ws layout: [partials fp32: BH_TOT*NCH*128*68] [reduced bf16: BH_TOT*128*66]
#define PART_ELEMS ((size_t)BH_TOT * NCH * KV_ROWS * PART_STRIDE)

// ---------------------------------------------------------------------------
// Phase 1 (v3): per-chunk partial KV[128][65] written with PLAIN stores into a
// private workspace slice — the 8.5M contended device-scope atomicAdds of v2
// (~100 us, the dominant fixed cost) are gone. Loop structure unchanged from
// v2 (8 rounds, register prefetch, 8 waves, full occupancy).
// ---------------------------------------------------------------------------
__global__ __launch_bounds__(512, 8) void fla_ph1(const float* __restrict__ K,
                                                  const float* __restrict__ V,
                                                  float* __restrict__ kvp) {
  const int blk = blockIdx.x;
  const int bh = blk / NCH;
  const int ch = blk % NCH;
  const float* Kp = K + (size_t)bh * SEQ * DIM + (size_t)ch * CHN * DIM;
  const float* Vp = V + (size_t)bh * SEQ * DIM + (size_t)ch * CHN * DIM;

  __shared__ __bf16 Kb[ROWS][68];   // 68-pad: frag reads land 2-way (free)
  __shared__ __bf16 Vb[ROWS][68];

  const int tid = threadIdx.x;
  const int lane = tid & 63;
  const int w = tid >> 6;           // 0..7: feature tile (features w*16..w*16+15)
  const int quad = lane >> 4;
  const int col = lane & 15;

  // staging geometry: 1024 float4 per array, 2 per thread
  const int r0 = tid >> 4;          // 0..31
  const int c0 = (tid & 15) << 2;   // 0,4,..,60
  const int off0 = r0 * DIM + c0;
  const int off1 = off0 + 32 * DIM; // rows 32..63

  f32x4 acc[5];
#pragma unroll
  for (int nt = 0; nt < 5; ++nt) acc[nt] = (f32x4){0.f, 0.f, 0.f, 0.f};

  // constant B fragment for the ones-column (global col 64 of [V | 1])
  bf16x8 bones;
#pragma unroll
  for (int j = 0; j < 8; ++j) bones[j] = (__bf16)0.f;
  if (col == 0) {
#pragma unroll
    for (int j = 0; j < 8; ++j) bones[j] = (__bf16)1.0f;
  }

  const int kcol = ((w & 3) << 4) + col;  // K column feeding this wave's feature
  const bool neg = (w >= 4);              // waves 4..7: features 64..127 = relu(-K)

  // prologue: tile 0 loads in flight
  float4 pk0 = *(const float4*)(Kp + off0);
  float4 pk1 = *(const float4*)(Kp + off1);
  float4 pv0 = *(const float4*)(Vp + off0);
  float4 pv1 = *(const float4*)(Vp + off1);

  for (int s = 0; s < NR; ++s) {
    // convert current tile (implicit vmcnt wait on the 4 loads)
    bf16x4 kb0, kb1, vb0, vb1;
    kb0[0] = (__bf16)pk0.x; kb0[1] = (__bf16)pk0.y; kb0[2] = (__bf16)pk0.z; kb0[3] = (__bf16)pk0.w;
    kb1[0] = (__bf16)pk1.x; kb1[1] = (__bf16)pk1.y; kb1[2] = (__bf16)pk1.z; kb1[3] = (__bf16)pk1.w;
    vb0[0] = (__bf16)pv0.x; vb0[1] = (__bf16)pv0.y; vb0[2] = (__bf16)pv0.z; vb0[3] = (__bf16)pv0.w;
    vb1[0] = (__bf16)pv1.x; vb1[1] = (__bf16)pv1.y; vb1[2] = (__bf16)pv1.z; vb1[3] = (__bf16)pv1.w;

    // prefetch tile s+1 into the now-free registers
    if (s + 1 < NR) {
      const float* Kn = Kp + (s + 1) * ROWS * DIM;
      const float* Vn = Vp + (s + 1) * ROWS * DIM;
      pk0 = *(const float4*)(Kn + off0);
      pk1 = *(const float4*)(Kn + off1);
      pv0 = *(const float4*)(Vn + off0);
      pv1 = *(const float4*)(Vn + off1);
    }

    __syncthreads();  // previous round's LDS readers done
    *(bf16x4*)&Kb[r0][c0]      = kb0;
    *(bf16x4*)&Kb[r0 + 32][c0] = kb1;
    *(bf16x4*)&Vb[r0][c0]      = vb0;
    *(bf16x4*)&Vb[r0 + 32][c0] = vb1;
    __syncthreads();

    // compute: two 32-row K-slabs
#pragma unroll
    for (int sl = 0; sl < 2; ++sl) {
      bf16x8 a;
#pragma unroll
      for (int j = 0; j < 8; ++j) {
        int rr = sl * 32 + quad * 8 + j;
        float kv = (float)Kb[rr][kcol];
        if (neg) kv = -kv;
        a[j] = (__bf16)fmaxf(kv, 0.f);
      }
#pragma unroll
      for (int nt = 0; nt < 4; ++nt) {
        bf16x8 b;
#pragma unroll
        for (int j = 0; j < 8; ++j)
          b[j] = Vb[sl * 32 + quad * 8 + j][col + nt * 16];
        acc[nt] = __builtin_amdgcn_mfma_f32_16x16x32_bf16(a, b, acc[nt], 0, 0, 0);
      }
      acc[4] = __builtin_amdgcn_mfma_f32_16x16x32_bf16(a, bones, acc[4], 0, 0, 0);
    }
  }

  // C/D layout: col = lane&15 (N), row = quad*4 + reg (M)  [measured m89/m91]
  // Plain stores into this block's private partial slice — no atomics.
  float* dst = kvp + ((size_t)bh * NCH + ch) * KV_ROWS * PART_STRIDE;
  const int feat = w * 16 + quad * 4;
#pragma unroll
  for (int nt = 0; nt < 5; ++nt) {
    int c = nt * 16 + col;
    if (c <= 64) {
#pragma unroll
      for (int r = 0; r < 4; ++r)
        dst[(size_t)(feat + r) * PART_STRIDE + c] = acc[nt][r];
    }
  }
}

// ---------------------------------------------------------------------------
// Reduce: sum the 16 per-chunk fp32 partials -> bf16 [128][66] per bh
// (col 64 = Ksum, col 65 = 0 pad). One thread per output element; the 16
// chunk loads are independent (full MLP), consecutive lanes read consecutive
// cols (coalesced). ~36 MB reads, ~1 MB writes.
// ---------------------------------------------------------------------------
__global__ __launch_bounds__(256) void fla_red(const float* __restrict__ kvp,
                                               __bf16* __restrict__ kvr) {
  const int idx = blockIdx.x * 256 + threadIdx.x;   // 64*128*66 total
  const int bh = idx / (KV_ROWS * RED_COLS);
  const int rem = idx - bh * (KV_ROWS * RED_COLS);
  const int r = rem / RED_COLS;
  const int c = rem - r * RED_COLS;
  float s = 0.f;
  if (c <= 64) {
    const float* src = kvp + (size_t)bh * NCH * KV_ROWS * PART_STRIDE
                     + (size_t)r * PART_STRIDE + c;
#pragma unroll
    for (int ch = 0; ch < NCH; ++ch)
      s += src[(size_t)ch * KV_ROWS * PART_STRIDE];
  }
  kvr[idx] = (__bf16)s;
}

// ---------------------------------------------------------------------------
// Phase 2: out[n][m] = (Qf[n] @ KV[:,m]) / (Qf[n] @ Ksum + 1e-6)
// Source is now the reduced bf16 buffer in the exact LDS layout -> prologue
// is a straight 16.9 KB vector copy (no fp32 load + convert).
// ---------------------------------------------------------------------------
__global__ __launch_bounds__(256) void fla_ph2(const float* __restrict__ Q,
                                               const __bf16* __restrict__ kvr,
                                               float* __restrict__ out) {
  const int blk = blockIdx.x;
  const int bh = blk >> 5;
  const int rb = blk & 31;                  // 32 row-blocks of 256 rows
  const float* Qp = Q + (size_t)bh * SEQ * DIM + (size_t)rb * 256 * DIM;
  float* Op = out + (size_t)bh * SEQ * DIM + (size_t)rb * 256 * DIM;

  __shared__ __align__(16) __bf16 kvb[KV_ROWS][RED_COLS];
  {
    const f32x4* s = (const f32x4*)(kvr + (size_t)bh * KV_ROWS * RED_COLS);
    f32x4* d = (f32x4*)&kvb[0][0];
    for (int i = threadIdx.x; i < KV_ROWS * RED_COLS * 2 / 16; i += 256)
      d[i] = s[i];
  }
  __syncthreads();

  const int lane = threadIdx.x & 63;
  const int w = threadIdx.x >> 6;
  const int quad = lane >> 4;
  const int col = lane & 15;

  // B[k][n]: k = kt*32 + quad*8 + j, n = col (+16*nt)
  bf16x8 bfr[4][5];
#pragma unroll
  for (int kt = 0; kt < 4; ++kt) {
#pragma unroll
    for (int j = 0; j < 8; ++j) {
      int k = kt * 32 + quad * 8 + j;
      bfr[kt][0][j] = kvb[k][col];
      bfr[kt][1][j] = kvb[k][col + 16];
      bfr[kt][2][j] = kvb[k][col + 32];
      bfr[kt][3][j] = kvb[k][col + 48];
      bfr[kt][4][j] = (col == 0) ? kvb[k][64] : (__bf16)0.f;
    }
  }

#pragma unroll
  for (int mt = 0; mt < 4; ++mt) {
    // A-frag loads: lane reads Q[row = base + col][quad*8 .. +7] — the wave's
    // two dwordx4 per frag tile perfectly cover 16 rows x 128B contiguous.
    const float* qrow = Qp + (size_t)(w * 64 + mt * 16 + col) * DIM;
    float4 q0 = *(const float4*)(qrow + quad * 8);
    float4 q1 = *(const float4*)(qrow + quad * 8 + 4);
    float4 q2 = *(const float4*)(qrow + 32 + quad * 8);
    float4 q3 = *(const float4*)(qrow + 32 + quad * 8 + 4);
    float qv[16];
    *(float4*)&qv[0] = q0;  *(float4*)&qv[4] = q1;
    *(float4*)&qv[8] = q2;  *(float4*)&qv[12] = q3;
    bf16x8 a0, a1, a2, a3;   // kt0: relu(q0..31) kt1: relu(q32..63) kt2/3: relu(-q)
#pragma unroll
    for (int j = 0; j < 8; ++j) {
      a0[j] = (__bf16)fmaxf(qv[j], 0.f);
      a2[j] = (__bf16)fmaxf(-qv[j], 0.f);
      a1[j] = (__bf16)fmaxf(qv[8 + j], 0.f);
      a3[j] = (__bf16)fmaxf(-qv[8 + j], 0.f);
    }
    f32x4 acc[5];
#pragma unroll
    for (int nt = 0; nt < 5; ++nt) acc[nt] = (f32x4){0.f, 0.f, 0.f, 0.f};
#pragma unroll
    for (int nt = 0; nt < 5; ++nt) {
      acc[nt] = __builtin_amdgcn_mfma_f32_16x16x32_bf16(a0, bfr[0][nt], acc[nt], 0, 0, 0);
      acc[nt] = __builtin_amdgcn_mfma_f32_16x16x32_bf16(a1, bfr[1][nt], acc[nt], 0, 0, 0);
      acc[nt] = __builtin_amdgcn_mfma_f32_16x16x32_bf16(a2, bfr[2][nt], acc[nt], 0, 0, 0);
      acc[nt] = __builtin_amdgcn_mfma_f32_16x16x32_bf16(a3, bfr[3][nt], acc[nt], 0, 0, 0);
    }
    // normalizer lives in N-tile 4, col 0 → lane (quad<<4), same reg index
    float inv[4];
#pragma unroll
    for (int r = 0; r < 4; ++r) {
      float nrm = __shfl((float)acc[4][r], lane & 48, 64);
      inv[r] = 1.0f / (nrm + 1e-6f);
    }
    float* orow = Op + (size_t)(w * 64 + mt * 16) * DIM;
#pragma unroll
    for (int nt = 0; nt < 4; ++nt)
#pragma unroll
      for (int r = 0; r < 4; ++r)
        orow[(size_t)(quad * 4 + r) * DIM + nt * 16 + col] = acc[nt][r] * inv[r];
  }
}

extern "C" void kernel_launch(void* const* d_in, const int* in_sizes, int n_in,
                              void* d_out, int out_size, void* d_ws, size_t ws_size,
                              hipStream_t stream) {
  const float* Q = (const float*)d_in[0];
  const float* K = (const float*)d_in[1];
  const float* V = (const float*)d_in[2];
  float* out = (float*)d_out;
  float* kvp = (float*)d_ws;                       // partials: 35.65 MB fp32
  __bf16* kvr = (__bf16*)((float*)d_ws + PART_ELEMS);  // reduced: 1.05 MB bf16

  // no memset needed: every consumed element of kvp/kvr is written
  fla_ph1<<<dim3(BH_TOT * NCH), dim3(512), 0, stream>>>(K, V, kvp);
  fla_red<<<dim3(BH_TOT * KV_ROWS * RED_COLS / 256), dim3(256), 0, stream>>>(kvp, kvr);
  fla_ph2<<<dim3(BH_TOT * 32), dim3(256), 0, stream>>>(Q, kvr, out);
}